// Round 2
// baseline (1252.921 us; speedup 1.0000x reference)
//
#include <hip/hip_runtime.h>
#include <hip/hip_bf16.h>
#include <float.h>

// Problem constants
#define M_TOTAL 16384       // 16*1024 queries
#define N_CODES 8192
#define KDIM    256
// GEMM tiling
#define BM 128
#define BN 128
#define BK 16
#define LDS_STRIDE 132
#define NCHUNKS 8
#define NT_PER_CHUNK 8      // (8192/NCHUNKS)/BN

// ---------------------------------------------------------------------------
// Bit-exact emulation of numpy's fp32 pairwise sum of x[i]^2 over 256
// contiguous elements: top-level split 128+128, each 128-block summed with 8
// sequential accumulator chains combined ((r0+r1)+(r2+r3))+((r4+r5)+(r6+r7)).
// fp contract OFF so r += v*v is mul-then-add (numpy squares into a temp
// array first, rounding each square once).
// ---------------------------------------------------------------------------
__device__ __forceinline__ float np_pairwise_sumsq256(const float* __restrict__ p) {
    #pragma clang fp contract(off)
    float tot0, tot1;
    #pragma unroll
    for (int b = 0; b < 2; b++) {
        const float* a = p + b * 128;
        float r[8];
        #pragma unroll
        for (int j = 0; j < 8; j++) { const float v = a[j]; r[j] = v * v; }
        for (int i = 8; i < 128; i += 8) {
            #pragma unroll
            for (int j = 0; j < 8; j++) { const float v = a[i + j]; r[j] += v * v; }
        }
        const float res = ((r[0] + r[1]) + (r[2] + r[3])) + ((r[4] + r[5]) + (r[6] + r[7]));
        if (b == 0) tot0 = res; else tot1 = res;
    }
    return tot0 + tot1;
}

// Kernel 1a: e_sq[n], numpy-bit-exact. One thread per code row.
__global__ void esq_kernel(const float* __restrict__ emb, float* __restrict__ esq) {
    const int n = blockIdx.x * blockDim.x + threadIdx.x;
    if (n < N_CODES) esq[n] = np_pairwise_sumsq256(emb + (size_t)n * KDIM);
}

// Kernel 1b: q_sq[m], numpy-bit-exact. One thread per query row.
__global__ void qsq_kernel(const float* __restrict__ Q, float* __restrict__ qsq) {
    const int m = blockIdx.x * blockDim.x + threadIdx.x;
    if (m < M_TOTAL) qsq[m] = np_pairwise_sumsq256(Q + (size_t)m * KDIM);
}

// ---------------------------------------------------------------------------
// Kernel 2: fused distance-GEMM + per-chunk argmin partials.
// d(q,n) = fp32( fp32(q_sq + e_sq_n) - 2*dot )  -- emulates np's rounding,
// ties broken by lowest index (matches np.argmin first-occurrence).
// ---------------------------------------------------------------------------
union SMem {
    struct { float Qs[BK][LDS_STRIDE]; float Es[BK][LDS_STRIDE]; } st;
    struct { float v[BM][16]; int idx[BM][16]; } red;
};

__global__ __launch_bounds__(256, 4)
void argmin_partial_kernel(const float* __restrict__ Q, const float* __restrict__ E,
                           const float* __restrict__ esq, const float* __restrict__ qsq,
                           float* __restrict__ wmin, int* __restrict__ widx) {
    __shared__ SMem sm;
    const int tid = threadIdx.x;
    const int tx = tid & 15, ty = tid >> 4;
    const int m0 = blockIdx.x * BM;
    const int chunk = blockIdx.y;

    // per-thread query rows and their (np-bit-exact) q_sq values
    float qs_r[8];
    #pragma unroll
    for (int i = 0; i < 8; i++) {
        const int mi = (i < 4) ? (ty * 4 + i) : (64 + ty * 4 + (i - 4));
        qs_r[i] = qsq[m0 + mi];
    }

    float minv[8]; int mini[8];
    #pragma unroll
    for (int i = 0; i < 8; i++) { minv[i] = FLT_MAX; mini[i] = 0x7fffffff; }

    const int row0 = tid >> 2;
    const int kc   = (tid & 3) * 4;

    for (int nt = 0; nt < NT_PER_CHUNK; nt++) {
        const int n0 = chunk * (BN * NT_PER_CHUNK) + nt * BN;
        float acc[8][8];
        #pragma unroll
        for (int i = 0; i < 8; i++)
            #pragma unroll
            for (int j = 0; j < 8; j++) acc[i][j] = 0.f;

        for (int k0 = 0; k0 < KDIM; k0 += BK) {
            #pragma unroll
            for (int r = 0; r < 2; r++) {
                const int row = row0 + r * 64;
                const float4 qa = *(const float4*)(Q + (size_t)(m0 + row) * KDIM + k0 + kc);
                sm.st.Qs[kc + 0][row] = qa.x; sm.st.Qs[kc + 1][row] = qa.y;
                sm.st.Qs[kc + 2][row] = qa.z; sm.st.Qs[kc + 3][row] = qa.w;
                const float4 ea = *(const float4*)(E + (size_t)(n0 + row) * KDIM + k0 + kc);
                sm.st.Es[kc + 0][row] = ea.x; sm.st.Es[kc + 1][row] = ea.y;
                sm.st.Es[kc + 2][row] = ea.z; sm.st.Es[kc + 3][row] = ea.w;
            }
            __syncthreads();
            #pragma unroll
            for (int kk = 0; kk < BK; kk++) {
                const float4 a0 = *(const float4*)&sm.st.Qs[kk][ty * 4];
                const float4 a1 = *(const float4*)&sm.st.Qs[kk][64 + ty * 4];
                const float4 b0 = *(const float4*)&sm.st.Es[kk][tx * 4];
                const float4 b1 = *(const float4*)&sm.st.Es[kk][64 + tx * 4];
                const float a[8] = {a0.x, a0.y, a0.z, a0.w, a1.x, a1.y, a1.z, a1.w};
                const float b[8] = {b0.x, b0.y, b0.z, b0.w, b1.x, b1.y, b1.z, b1.w};
                #pragma unroll
                for (int i = 0; i < 8; i++)
                    #pragma unroll
                    for (int j = 0; j < 8; j++)
                        acc[i][j] = fmaf(a[i], b[j], acc[i][j]);
            }
            __syncthreads();
        }
        // argmin epilogue: emulate np's two-step fp32 rounding
        #pragma unroll
        for (int j = 0; j < 8; j++) {
            const int nl = (j < 4) ? (tx * 4 + j) : (64 + tx * 4 + (j - 4));
            const int ng = n0 + nl;
            const float es = esq[ng];
            #pragma unroll
            for (int i = 0; i < 8; i++) {
                float d;
                {
                    #pragma clang fp contract(off)
                    const float t1 = qs_r[i] + es;       // rounds at ~256 -> coarse grid
                    d = t1 - 2.0f * acc[i][j];           // 2*acc exact; one more rounding
                }
                if (d < minv[i] || (d == minv[i] && ng < mini[i])) { minv[i] = d; mini[i] = ng; }
            }
        }
    }

    __syncthreads();
    #pragma unroll
    for (int i = 0; i < 8; i++) {
        const int m = (i < 4) ? (ty * 4 + i) : (64 + ty * 4 + (i - 4));
        sm.red.v[m][tx] = minv[i];
        sm.red.idx[m][tx] = mini[i];
    }
    __syncthreads();
    if (tid < BM) {
        float bv = FLT_MAX; int bi = 0x7fffffff;
        #pragma unroll
        for (int t = 0; t < 16; t++) {
            const float v = sm.red.v[tid][t]; const int id = sm.red.idx[tid][t];
            if (v < bv || (v == bv && id < bi)) { bv = v; bi = id; }
        }
        wmin[chunk * M_TOTAL + m0 + tid] = bv;
        widx[chunk * M_TOTAL + m0 + tid] = bi;
    }
}

// ---------------------------------------------------------------------------
// Kernel 3: merge chunk partials; write index (as float), gather embedding
// row -> straight-through output, accumulate vq_loss. One wave per query.
// ---------------------------------------------------------------------------
__global__ void finalize_kernel(const float* __restrict__ Q, const float* __restrict__ E,
                                const float* __restrict__ wmin, const int* __restrict__ widx,
                                float* __restrict__ out) {
    const int q = blockIdx.x;
    const int lane = threadIdx.x;
    float bv = FLT_MAX; int bi = 0x7fffffff;
    #pragma unroll
    for (int c = 0; c < NCHUNKS; c++) {
        const float v = wmin[c * M_TOTAL + q]; const int id = widx[c * M_TOTAL + q];
        if (v < bv || (v == bv && id < bi)) { bv = v; bi = id; }
    }
    if (lane == 0) out[q] = (float)bi;

    const float4 qv = *(const float4*)(Q + (size_t)q * KDIM + lane * 4);
    const float4 ev = *(const float4*)(E + (size_t)bi * KDIM + lane * 4);
    float4 st;
    {
        #pragma clang fp contract(off)
        st.x = qv.x + (ev.x - qv.x);
        st.y = qv.y + (ev.y - qv.y);
        st.z = qv.z + (ev.z - qv.z);
        st.w = qv.w + (ev.w - qv.w);
    }
    *(float4*)(out + M_TOTAL + (size_t)q * KDIM + lane * 4) = st;

    const float dx = qv.x - ev.x, dy = qv.y - ev.y, dz = qv.z - ev.z, dw = qv.w - ev.w;
    float s = dx * dx + dy * dy + dz * dz + dw * dw;
    #pragma unroll
    for (int off = 32; off > 0; off >>= 1) s += __shfl_down(s, off);
    if (lane == 0) {
        // vq_loss = 1.25 * mean((q - e)^2)
        atomicAdd(out + M_TOTAL + (size_t)M_TOTAL * KDIM,
                  s * (1.25f / (float)((size_t)M_TOTAL * KDIM)));
    }
}

extern "C" void kernel_launch(void* const* d_in, const int* in_sizes, int n_in,
                              void* d_out, int out_size, void* d_ws, size_t ws_size,
                              hipStream_t stream) {
    const float* Q = (const float*)d_in[0];   // [16,1024,256] fp32
    const float* E = (const float*)d_in[1];   // [8192,256] fp32
    float* out = (float*)d_out;               // [16384 idx][4194304 quantized][1 loss]

    float* wmin = (float*)d_ws;                                            // 131072 f
    int*   widx = (int*)((char*)d_ws + (size_t)NCHUNKS * M_TOTAL * 4);     // 131072 i
    float* esq  = (float*)((char*)d_ws + (size_t)2 * NCHUNKS * M_TOTAL * 4);   // 8192 f
    float* qsq  = esq + N_CODES;                                           // 16384 f

    hipMemsetAsync(out + M_TOTAL + (size_t)M_TOTAL * KDIM, 0, sizeof(float), stream);

    esq_kernel<<<(N_CODES + 255) / 256, 256, 0, stream>>>(E, esq);
    qsq_kernel<<<(M_TOTAL + 255) / 256, 256, 0, stream>>>(Q, qsq);
    argmin_partial_kernel<<<dim3(M_TOTAL / BM, NCHUNKS), 256, 0, stream>>>(Q, E, esq, qsq, wmin, widx);
    finalize_kernel<<<M_TOTAL, 64, 0, stream>>>(Q, E, wmin, widx, out);
}